// Round 2
// baseline (945.213 us; speedup 1.0000x reference)
//
#include <hip/hip_runtime.h>
#include <stdint.h>

// GATConv fused, v2: fp16 2-term S = (Qh+Ql)·Kh, bit-packed adjacency,
// flash kernel with 2x2 wave tiling, single staging pass + 4 barriers/iter.
// ws layout (58 MB): [0,8) Xh/Xl (dead after qkv) then Abits; [8,9) W splits;
// [9,13) Qh; [13,17) Ql; [17,21) Kh; [21,25) Vt; [25,57) pO; [57,..) pM/pL.

typedef _Float16 f16;
typedef unsigned short u16;
typedef unsigned long long u64;
typedef __attribute__((ext_vector_type(8))) _Float16 f16x8;
typedef __attribute__((ext_vector_type(4))) float f32x4;

#define NN 8192
#define DD 256
#define BR 64
#define BC 64
#define CCH 4
#define COLS (NN / CCH)  // 2048
#define NIT (COLS / BC)  // 32

#define MFMA(a, b, c) __builtin_amdgcn_mfma_f32_16x16x32_f16((a), (b), (c), 0, 0, 0)

__device__ __forceinline__ void gl2lds16(const void* g, void* l) {
    __builtin_amdgcn_global_load_lds(
        (const __attribute__((address_space(1))) unsigned int*)g,
        (__attribute__((address_space(3))) unsigned int*)l, 16, 0, 0);
}

__device__ __forceinline__ u16 f16bits(f16 h) {
    union { f16 h; u16 u; } c;
    c.h = h;
    return c.u;
}

// ---------------- split X to fp16 hi/lo ----------------
__global__ void splitX_kernel(const float* __restrict__ X, f16* __restrict__ Xh,
                              f16* __restrict__ Xl, int n) {
    int i = blockIdx.x * blockDim.x + threadIdx.x;
    if (i < n) {
        float x = X[i];
        f16 h = (f16)x;
        Xh[i] = h;
        Xl[i] = (f16)(x - (float)h);
    }
}

// W[k][n] (3 mats 256x256) -> Wt[(mat*256+n)][k] fp16 hi/lo (transposed, B-frag order)
__global__ void splitW_kernel(const float* __restrict__ Wq, const float* __restrict__ Wk,
                              const float* __restrict__ Wv, f16* __restrict__ WtH,
                              f16* __restrict__ WtL) {
    int i = blockIdx.x * blockDim.x + threadIdx.x;  // 3*65536
    const int mat = i >> 16;
    const int k = (i >> 8) & 255;
    const int n = i & 255;
    const float* W = (mat == 0) ? Wq : ((mat == 1) ? Wk : Wv);
    float v = W[k * 256 + n];
    f16 h = (f16)v;
    size_t o = (size_t)(mat * 256 + n) * 256 + k;
    WtH[o] = h;
    WtL[o] = (f16)(v - (float)h);
}

// ---------------- pack adjacency to bitmask (self-loop OR'd in) ----------------
__global__ void packA_kernel(const int* __restrict__ A, u64* __restrict__ Ab) {
    const int gid = blockIdx.x * 4 + (threadIdx.x >> 6);
    const int lane = threadIdx.x & 63;
    const int row = gid >> 7;   // 8192 rows
    const int g = gid & 127;    // 128 groups of 64 cols
    const int col = g * 64 + lane;
    const int a = A[(size_t)row * NN + col];
    const u64 m = __ballot(a != 0 || col == row);
    if (lane == 0) Ab[(size_t)row * 128 + g] = m;
}

// ---------------- QKV GEMM (3-term fp16, fp32-accurate) ----------------
// grid (128 row-tiles, 6 n-groups of 128). 4 waves x 16 rows. X frags in regs,
// W streamed from L2 (384 KB, hot across 128 row-blocks).
__global__ __launch_bounds__(256) void qkv_kernel(
    const f16* __restrict__ Xh, const f16* __restrict__ Xl,
    const f16* __restrict__ WtH, const f16* __restrict__ WtL,
    f16* __restrict__ Qh, f16* __restrict__ Ql,
    f16* __restrict__ Kh, f16* __restrict__ Vt) {
    const int lane = threadIdx.x & 63;
    const int w = threadIdx.x >> 6;
    const int l15 = lane & 15;
    const int quad = lane >> 4;
    const int r0 = blockIdx.x * 64;
    const int nbase = blockIdx.y * 128;  // 0..640

    f16x8 xh[8], xl[8];
    const size_t xb = (size_t)(r0 + w * 16 + l15) * DD + quad * 8;
#pragma unroll
    for (int kc = 0; kc < 8; ++kc) {
        xh[kc] = *(const f16x8*)(Xh + xb + kc * 32);
        xl[kc] = *(const f16x8*)(Xl + xb + kc * 32);
    }

    const int mat = nbase >> 8;  // 0=Q, 1=K, 2=V
    const int orow = r0 + w * 16 + quad * 4;

#pragma unroll
    for (int nt = 0; nt < 8; ++nt) {
        f32x4 acc = {0.f, 0.f, 0.f, 0.f};
        const int n = nbase + nt * 16 + l15;
        const size_t wb = (size_t)n * DD + quad * 8;
#pragma unroll
        for (int kc = 0; kc < 8; ++kc) {
            const f16x8 wh = *(const f16x8*)(WtH + wb + kc * 32);
            const f16x8 wl = *(const f16x8*)(WtL + wb + kc * 32);
            acc = MFMA(xh[kc], wh, acc);
            acc = MFMA(xh[kc], wl, acc);
            acc = MFMA(xl[kc], wh, acc);
        }
        const int col = (nbase & 255) + nt * 16 + l15;
        if (mat == 0) {
#pragma unroll
            for (int rg = 0; rg < 4; ++rg) {
                const float v = acc[rg];
                const f16 h = (f16)v;
                Qh[(size_t)(orow + rg) * DD + col] = h;
                Ql[(size_t)(orow + rg) * DD + col] = (f16)(v - (float)h);
            }
        } else if (mat == 1) {
#pragma unroll
            for (int rg = 0; rg < 4; ++rg) Kh[(size_t)(orow + rg) * DD + col] = (f16)acc[rg];
        } else {
            ushort4 pk;
            pk.x = f16bits((f16)acc[0]);
            pk.y = f16bits((f16)acc[1]);
            pk.z = f16bits((f16)acc[2]);
            pk.w = f16bits((f16)acc[3]);
            *(ushort4*)(Vt + (size_t)col * NN + orow) = pk;  // transposed [n][row]
        }
    }
}

// ---------------- flash kernel ----------------
// grid (128 row-tiles, 4 col-chunks). 4 waves: (rg = w>>1) row-half, (ch = w&1)
// col-half for S / n-half for PV. Single staging pass, 4 barriers/iter.
__global__ __launch_bounds__(256, 2) void flash_kernel(
    const f16* __restrict__ Qh, const f16* __restrict__ Ql,
    const f16* __restrict__ Kh, const f16* __restrict__ Vt,
    const u64* __restrict__ Ab,
    float* __restrict__ pO, float* __restrict__ pM, float* __restrict__ pL) {
    __shared__ f16 Klds[64 * 256];   // 32 KB, [j][k], 16B-block XOR swizzle per row
    __shared__ f16 Vlds[256 * 64];   // 32 KB, [n][j], swizzled
    __shared__ f16 Plds[64 * 72];    // 9 KB, row-major, +8 pad
    __shared__ float smax[2][64];
    __shared__ float ssum[2][64];

    const int tid = threadIdx.x;
    const int lane = tid & 63;
    const int w = tid >> 6;
    const int l15 = lane & 15;
    const int quad = lane >> 4;
    const int rg = w >> 1;
    const int ch = w & 1;
    const int r0 = blockIdx.x * BR;
    const int cch = blockIdx.y;
    const int col0 = cch * COLS;

    // Q fragments resident (A-layout: m=l15, k=quad*8+i), hi+lo fp16
    f16x8 qh[2][8], ql[2][8];
#pragma unroll
    for (int mt = 0; mt < 2; ++mt) {
        const size_t qb = (size_t)(r0 + rg * 32 + mt * 16 + l15) * DD + quad * 8;
#pragma unroll
        for (int kc = 0; kc < 8; ++kc) {
            qh[mt][kc] = *(const f16x8*)(Qh + qb + kc * 32);
            ql[mt][kc] = *(const f16x8*)(Ql + qb + kc * 32);
        }
    }

    const f32x4 fzero = {0.f, 0.f, 0.f, 0.f};
    f32x4 accO[2][8];
#pragma unroll
    for (int mt = 0; mt < 2; ++mt)
#pragma unroll
        for (int nt = 0; nt < 8; ++nt) accO[mt][nt] = fzero;
    float mrow[2][4], lrow[2][4];
#pragma unroll
    for (int mt = 0; mt < 2; ++mt)
#pragma unroll
        for (int r = 0; r < 4; ++r) {
            mrow[mt][r] = -1e30f;
            lrow[mt][r] = 0.f;
        }

#pragma unroll 1
    for (int it = 0; it < NIT; ++it) {
        const int j0 = col0 + it * BC;

        // stage K tile (wave w: rows w*16..+16); source-swizzled 16B blocks
#pragma unroll
        for (int i = 0; i < 8; ++i) {
            const int r = w * 16 + i * 2 + (lane >> 5);
            gl2lds16(Kh + (size_t)(j0 + r) * DD + (((lane & 31) ^ (r & 7)) * 8),
                     &Klds[(w * 16 + i * 2) * 256]);
        }
        // stage V tile (wave w: n rows w*64..+64)
#pragma unroll
        for (int i = 0; i < 8; ++i) {
            const int n = w * 64 + i * 8 + (lane >> 3);
            gl2lds16(Vt + (size_t)n * NN + j0 + (((lane & 7) ^ (lane >> 3)) * 8),
                     &Vlds[(w * 64 + i * 8) * 64]);
        }
        // adjacency bits for this wave's 32 rows x 32 cols (bit (mt*8+rgi*2+jt))
        unsigned msk = 0;
#pragma unroll
        for (int mt = 0; mt < 2; ++mt)
#pragma unroll
            for (int rgi = 0; rgi < 4; ++rgi) {
                const int row = r0 + rg * 32 + mt * 16 + quad * 4 + rgi;
                const u64 aw = Ab[(size_t)row * (NN / 64) + (j0 >> 6)];
                const int base = ch * 32;
                msk |= ((unsigned)((aw >> (base + l15)) & 1ull)) << (mt * 8 + rgi * 2);
                msk |= ((unsigned)((aw >> (base + 16 + l15)) & 1ull)) << (mt * 8 + rgi * 2 + 1);
            }
        __syncthreads();  // B1: staging visible

        // S = (Qh+Ql) · Kh^T   (this wave: 32 rows x 32 cols)
        f32x4 accS[2][2];
#pragma unroll
        for (int mt = 0; mt < 2; ++mt)
#pragma unroll
            for (int jt = 0; jt < 2; ++jt) accS[mt][jt] = fzero;
#pragma unroll
        for (int kc = 0; kc < 8; ++kc)
#pragma unroll
            for (int jt = 0; jt < 2; ++jt) {
                const int r = ch * 32 + jt * 16 + l15;
                const int blk = (kc * 4 + quad) ^ (r & 7);
                const f16x8 kf = *(const f16x8*)&Klds[r * 256 + blk * 8];
#pragma unroll
                for (int mt = 0; mt < 2; ++mt) {
                    accS[mt][jt] = MFMA(qh[mt][kc], kf, accS[mt][jt]);
                    accS[mt][jt] = MFMA(ql[mt][kc], kf, accS[mt][jt]);
                }
            }

        // mask + per-half row max
        float mx[2][4];
#pragma unroll
        for (int mt = 0; mt < 2; ++mt)
#pragma unroll
            for (int rgi = 0; rgi < 4; ++rgi) {
                const float s0 =
                    ((msk >> (mt * 8 + rgi * 2)) & 1) ? accS[mt][0][rgi] : -1e30f;
                const float s1 =
                    ((msk >> (mt * 8 + rgi * 2 + 1)) & 1) ? accS[mt][1][rgi] : -1e30f;
                accS[mt][0][rgi] = s0;
                accS[mt][1][rgi] = s1;
                float m = fmaxf(s0, s1);
#pragma unroll
                for (int off = 1; off < 16; off <<= 1) m = fmaxf(m, __shfl_xor(m, off, 64));
                mx[mt][rgi] = m;
                if (l15 == 0) smax[ch][rg * 32 + mt * 16 + quad * 4 + rgi] = m;
            }
        __syncthreads();  // B2: halves' maxima visible

        // global max -> alpha, exp, P write, partial sums; rescale accO
#pragma unroll
        for (int mt = 0; mt < 2; ++mt)
#pragma unroll
            for (int rgi = 0; rgi < 4; ++rgi) {
                const int rloc = rg * 32 + mt * 16 + quad * 4 + rgi;
                const float mnew =
                    fmaxf(mrow[mt][rgi], fmaxf(mx[mt][rgi], smax[ch ^ 1][rloc]));
                const float al = __expf(mrow[mt][rgi] - mnew);
                mrow[mt][rgi] = mnew;
                float rs = 0.f;
#pragma unroll
                for (int jt = 0; jt < 2; ++jt) {
                    const float sv = accS[mt][jt][rgi];
                    const float e =
                        ((msk >> (mt * 8 + rgi * 2 + jt)) & 1) ? __expf(sv - mnew) : 0.f;
                    rs += e;
                    Plds[rloc * 72 + ch * 32 + jt * 16 + l15] = (f16)e;
                }
#pragma unroll
                for (int off = 1; off < 16; off <<= 1) rs += __shfl_xor(rs, off, 64);
                if (l15 == 0) ssum[ch][rloc] = rs;
                lrow[mt][rgi] = lrow[mt][rgi] * al + rs;
#pragma unroll
                for (int nt = 0; nt < 8; ++nt) accO[mt][nt][rgi] *= al;
            }
        __syncthreads();  // B3: P + partial sums visible

#pragma unroll
        for (int mt = 0; mt < 2; ++mt)
#pragma unroll
            for (int rgi = 0; rgi < 4; ++rgi)
                lrow[mt][rgi] += ssum[ch ^ 1][rg * 32 + mt * 16 + quad * 4 + rgi];

        // PV: this wave: its 32 P-rows x n-half (ch*128..+128)
        f16x8 pf[2][2];
#pragma unroll
        for (int mt = 0; mt < 2; ++mt)
#pragma unroll
            for (int kc = 0; kc < 2; ++kc)
                pf[mt][kc] =
                    *(const f16x8*)&Plds[(rg * 32 + mt * 16 + l15) * 72 + kc * 32 + quad * 8];
#pragma unroll
        for (int nt = 0; nt < 8; ++nt)
#pragma unroll
            for (int kc = 0; kc < 2; ++kc) {
                const int n = ch * 128 + nt * 16 + l15;
                const int blk = (kc * 4 + quad) ^ (n & 7);
                const f16x8 vf = *(const f16x8*)&Vlds[n * 64 + blk * 8];
#pragma unroll
                for (int mt = 0; mt < 2; ++mt) accO[mt][nt] = MFMA(pf[mt][kc], vf, accO[mt][nt]);
            }
        __syncthreads();  // B4: LDS free for next iter's staging
    }

    // write partials
#pragma unroll
    for (int mt = 0; mt < 2; ++mt)
#pragma unroll
        for (int nt = 0; nt < 8; ++nt)
#pragma unroll
            for (int rgi = 0; rgi < 4; ++rgi) {
                const int grow = r0 + rg * 32 + mt * 16 + quad * 4 + rgi;
                pO[((size_t)cch * NN + grow) * DD + ch * 128 + nt * 16 + l15] =
                    accO[mt][nt][rgi];
            }
    if (ch == 0 && l15 == 0) {
#pragma unroll
        for (int mt = 0; mt < 2; ++mt)
#pragma unroll
            for (int rgi = 0; rgi < 4; ++rgi) {
                const int grow = r0 + rg * 32 + mt * 16 + quad * 4 + rgi;
                pM[(size_t)cch * NN + grow] = mrow[mt][rgi];
                pL[(size_t)cch * NN + grow] = lrow[mt][rgi];
            }
    }
}

// ---------------- merge partials ----------------
__global__ __launch_bounds__(256) void merge_kernel(const float* __restrict__ pO,
                                                    const float* __restrict__ pM,
                                                    const float* __restrict__ pL,
                                                    float* __restrict__ out) {
    const int row = blockIdx.x;
    const int n = threadIdx.x;
    float mc[CCH], lc[CCH];
    float M = -3e38f;
#pragma unroll
    for (int c = 0; c < CCH; ++c) {
        mc[c] = pM[(size_t)c * NN + row];
        lc[c] = pL[(size_t)c * NN + row];
        M = fmaxf(M, mc[c]);
    }
    float L = 0.f, acc = 0.f;
#pragma unroll
    for (int c = 0; c < CCH; ++c) {
        const float wgt = __expf(mc[c] - M);
        L += wgt * lc[c];
        acc += wgt * pO[((size_t)c * NN + row) * DD + n];
    }
    out[(size_t)row * DD + n] = acc / L;
}

extern "C" void kernel_launch(void* const* d_in, const int* in_sizes, int n_in,
                              void* d_out, int out_size, void* d_ws, size_t ws_size,
                              hipStream_t stream) {
    const float* X = (const float*)d_in[0];
    const int* A = (const int*)d_in[1];
    const float* Wq = (const float*)d_in[2];
    const float* Wk = (const float*)d_in[3];
    const float* Wv = (const float*)d_in[4];
    float* out = (float*)d_out;

    char* ws = (char*)d_ws;
    const size_t MB = 1ull << 20;
    f16* Xh = (f16*)(ws + 0 * MB);
    f16* Xl = (f16*)(ws + 4 * MB);
    u64* Ab = (u64*)(ws + 0 * MB);  // overwrites Xh/Xl AFTER qkv consumed them
    f16* WtH = (f16*)(ws + 8 * MB);
    f16* WtL = (f16*)(ws + 8 * MB + 512 * 1024);
    f16* Qh = (f16*)(ws + 9 * MB);
    f16* Ql = (f16*)(ws + 13 * MB);
    f16* Kh = (f16*)(ws + 17 * MB);
    f16* Vt = (f16*)(ws + 21 * MB);
    float* pO = (float*)(ws + 25 * MB);
    float* pM = (float*)(ws + 57 * MB);
    float* pL = (float*)(ws + 57 * MB + 256 * 1024);
    (void)ws_size; (void)in_sizes; (void)n_in; (void)out_size;

    splitX_kernel<<<(NN * DD + 255) / 256, 256, 0, stream>>>(X, Xh, Xl, NN * DD);
    splitW_kernel<<<(3 * 256 * 256) / 256, 256, 0, stream>>>(Wq, Wk, Wv, WtH, WtL);
    qkv_kernel<<<dim3(NN / 64, 6), 256, 0, stream>>>(Xh, Xl, WtH, WtL, Qh, Ql, Kh, Vt);
    packA_kernel<<<(NN / 64) * (NN / 64) * 64 / 4, 256, 0, stream>>>(A, Ab);
    flash_kernel<<<dim3(NN / BR, CCH), 256, 0, stream>>>(Qh, Ql, Kh, Vt, Ab, pO, pM, pL);
    merge_kernel<<<dim3(NN), 256, 0, stream>>>(pO, pM, pL, out);
}

// Round 3
// 590.147 us; speedup vs baseline: 1.6017x; 1.6017x over previous
//
#include <hip/hip_runtime.h>
#include <stdint.h>

// GATConv fused v3: fp16 2-term S = (Qh+Ql)·Kh, A fused into flash (no packA),
// per-wave full-row softmax (zero cross-wave exchange, 2 barriers/iter),
// cch pinned to XCD via linear block id, LDS-staged qkv.

typedef _Float16 f16;
typedef unsigned short u16;
typedef __attribute__((ext_vector_type(8))) _Float16 f16x8;
typedef __attribute__((ext_vector_type(4))) _Float16 f16x4;
typedef __attribute__((ext_vector_type(4))) float f32x4;

#define NN 8192
#define DD 256
#define BR 64
#define BC 64
#define CCH 4
#define COLS (NN / CCH)  // 2048
#define NIT (COLS / BC)  // 32

#define MFMA(a, b, c) __builtin_amdgcn_mfma_f32_16x16x32_f16((a), (b), (c), 0, 0, 0)

__device__ __forceinline__ void gl2lds16(const void* g, void* l) {
    __builtin_amdgcn_global_load_lds(
        (const __attribute__((address_space(1))) unsigned int*)g,
        (__attribute__((address_space(3))) unsigned int*)l, 16, 0, 0);
}

__device__ __forceinline__ u16 f16bits(f16 h) {
    union { f16 h; u16 u; } c;
    c.h = h;
    return c.u;
}

// ---------------- split X to fp16 hi/lo (4 elems/thread) ----------------
__global__ void splitX_kernel(const float4* __restrict__ X, f16x4* __restrict__ Xh,
                              f16x4* __restrict__ Xl) {
    const int i = blockIdx.x * blockDim.x + threadIdx.x;  // 524288
    const float4 v = X[i];
    const f16 h0 = (f16)v.x, h1 = (f16)v.y, h2 = (f16)v.z, h3 = (f16)v.w;
    f16x4 H = {h0, h1, h2, h3};
    f16x4 L = {(f16)(v.x - (float)h0), (f16)(v.y - (float)h1), (f16)(v.z - (float)h2),
               (f16)(v.w - (float)h3)};
    Xh[i] = H;
    Xl[i] = L;
}

// W[k][n] (3 mats 256x256) -> Wt[(mat*256+n)][k] fp16 hi/lo (transposed)
__global__ void splitW_kernel(const float* __restrict__ Wq, const float* __restrict__ Wk,
                              const float* __restrict__ Wv, f16* __restrict__ WtH,
                              f16* __restrict__ WtL) {
    const int i = blockIdx.x * blockDim.x + threadIdx.x;  // 3*65536
    const int mat = i >> 16;
    const int k = (i >> 8) & 255;
    const int n = i & 255;
    const float* W = (mat == 0) ? Wq : ((mat == 1) ? Wk : Wv);
    const float v = W[k * 256 + n];
    const f16 h = (f16)v;
    const size_t o = (size_t)(mat * 256 + n) * 256 + k;
    WtH[o] = h;
    WtL[o] = (f16)(v - (float)h);
}

// ---------------- QKV GEMM: LDS-staged W chunks, X frags in registers ----------------
// grid (128 row-blocks of 64, 3 mats). Each block loops 4 n-chunks of 64.
__global__ __launch_bounds__(256) void qkv_kernel(
    const f16* __restrict__ Xh, const f16* __restrict__ Xl,
    const f16* __restrict__ WtH, const f16* __restrict__ WtL,
    f16* __restrict__ Qh, f16* __restrict__ Ql,
    f16* __restrict__ Kh, f16* __restrict__ Vt) {
    __shared__ f16 Wh[64 * 256];  // 32 KB, row = local n, 16B blocks XOR-swizzled by row
    __shared__ f16 Wl[64 * 256];  // 32 KB
    const int lane = threadIdx.x & 63;
    const int w = threadIdx.x >> 6;
    const int l15 = lane & 15;
    const int quad = lane >> 4;
    const int r0 = blockIdx.x * 64;
    const int mat = blockIdx.y;

    f16x8 xh[8], xl[8];
    const size_t xb = (size_t)(r0 + w * 16 + l15) * DD + quad * 8;
#pragma unroll
    for (int kc = 0; kc < 8; ++kc) {
        xh[kc] = *(const f16x8*)(Xh + xb + kc * 32);
        xl[kc] = *(const f16x8*)(Xl + xb + kc * 32);
    }
    const int orow = r0 + w * 16 + quad * 4;

#pragma unroll 1
    for (int c = 0; c < 4; ++c) {
        const int nb = mat * 256 + c * 64;  // Wt global row base
#pragma unroll
        for (int i = 0; i < 8; ++i) {
            const int r = w * 16 + i * 2 + (lane >> 5);
            gl2lds16(WtH + (size_t)(nb + r) * DD + (((lane & 31) ^ (r & 7)) * 8),
                     &Wh[(w * 16 + i * 2) * 256]);
        }
#pragma unroll
        for (int i = 0; i < 8; ++i) {
            const int r = w * 16 + i * 2 + (lane >> 5);
            gl2lds16(WtL + (size_t)(nb + r) * DD + (((lane & 31) ^ (r & 7)) * 8),
                     &Wl[(w * 16 + i * 2) * 256]);
        }
        __syncthreads();

        const f32x4 fzero = {0.f, 0.f, 0.f, 0.f};
        f32x4 acc[4];
#pragma unroll
        for (int nt = 0; nt < 4; ++nt) acc[nt] = fzero;
#pragma unroll
        for (int kc = 0; kc < 8; ++kc)
#pragma unroll
            for (int nt = 0; nt < 4; ++nt) {
                const int r = nt * 16 + l15;
                const int blk = (((kc * 4 + quad) ^ (r & 7)) * 8);
                const f16x8 wh = *(const f16x8*)&Wh[r * 256 + blk];
                const f16x8 wl = *(const f16x8*)&Wl[r * 256 + blk];
                acc[nt] = MFMA(xh[kc], wh, acc[nt]);
                acc[nt] = MFMA(xh[kc], wl, acc[nt]);
                acc[nt] = MFMA(xl[kc], wh, acc[nt]);
            }

        if (mat == 0) {
#pragma unroll
            for (int nt = 0; nt < 4; ++nt)
#pragma unroll
                for (int rg = 0; rg < 4; ++rg) {
                    const int col = c * 64 + nt * 16 + l15;
                    const float v = acc[nt][rg];
                    const f16 h = (f16)v;
                    Qh[(size_t)(orow + rg) * DD + col] = h;
                    Ql[(size_t)(orow + rg) * DD + col] = (f16)(v - (float)h);
                }
        } else if (mat == 1) {
#pragma unroll
            for (int nt = 0; nt < 4; ++nt)
#pragma unroll
                for (int rg = 0; rg < 4; ++rg) {
                    const int col = c * 64 + nt * 16 + l15;
                    Kh[(size_t)(orow + rg) * DD + col] = (f16)acc[nt][rg];
                }
        } else {
#pragma unroll
            for (int nt = 0; nt < 4; ++nt) {
                const int n = c * 64 + nt * 16 + l15;
                ushort4 pk;
                pk.x = f16bits((f16)acc[nt][0]);
                pk.y = f16bits((f16)acc[nt][1]);
                pk.z = f16bits((f16)acc[nt][2]);
                pk.w = f16bits((f16)acc[nt][3]);
                *(ushort4*)(Vt + (size_t)n * NN + orow) = pk;  // Vt[n][row]
            }
        }
        __syncthreads();  // protect W LDS before next chunk's staging
    }
}

// ---------------- flash kernel ----------------
// grid 512 linear: cch = bid&3 (pins chunk to XCD pair), rowblk = bid>>2.
// 4 waves x 16 rows; wave owns full 64-col tile -> softmax is wave-local.
__global__ __launch_bounds__(256) void flash_kernel(
    const f16* __restrict__ Qh, const f16* __restrict__ Ql,
    const f16* __restrict__ Kh, const f16* __restrict__ Vt,
    const int* __restrict__ A,
    float* __restrict__ pO, float* __restrict__ pM, float* __restrict__ pL) {
    __shared__ f16 Klds[64 * 256];    // 32 KB, [j][k], 16B blocks XOR-swizzled by j&7
    __shared__ f16 Vlds[256 * 64];    // 32 KB, [n][j], swizzled by n&7
    __shared__ f16 Plds[4][16 * 88];  // 11 KB, per-wave, stride 88 f16 (16B-aligned rows)

    const int lane = threadIdx.x & 63;
    const int w = threadIdx.x >> 6;
    const int l15 = lane & 15;
    const int quad = lane >> 4;
    const int bid = blockIdx.x;
    const int cch = bid & 3;
    const int r0 = (bid >> 2) * BR;
    const int col0 = cch * COLS;

    // Q fragments resident (A-layout m=l15, k=quad*8+i), hi+lo
    f16x8 qh[8], ql[8];
    {
        const size_t qb = (size_t)(r0 + w * 16 + l15) * DD + quad * 8;
#pragma unroll
        for (int kc = 0; kc < 8; ++kc) {
            qh[kc] = *(const f16x8*)(Qh + qb + kc * 32);
            ql[kc] = *(const f16x8*)(Ql + qb + kc * 32);
        }
    }

    const f32x4 fzero = {0.f, 0.f, 0.f, 0.f};
    f32x4 accO[16];
#pragma unroll
    for (int i = 0; i < 16; ++i) accO[i] = fzero;
    float mrow[4], lrow[4];
#pragma unroll
    for (int r = 0; r < 4; ++r) {
        mrow[r] = -1e30f;
        lrow[r] = 0.f;
    }
    const int growb = r0 + w * 16 + quad * 4;
    f16* Pw = &Plds[w][0];

#pragma unroll 1
    for (int it = 0; it < NIT; ++it) {
        const int j0 = col0 + it * BC;

        // stage K tile (wave w: rows w*16..+16)
#pragma unroll
        for (int i = 0; i < 8; ++i) {
            const int r = w * 16 + i * 2 + (lane >> 5);
            gl2lds16(Kh + (size_t)(j0 + r) * DD + (((lane & 31) ^ (r & 7)) * 8),
                     &Klds[(w * 16 + i * 2) * 256]);
        }
        // stage V tile (wave w: n rows w*64..+64)
#pragma unroll
        for (int i = 0; i < 8; ++i) {
            const int n = w * 64 + i * 8 + (lane >> 3);
            gl2lds16(Vt + (size_t)n * NN + j0 + (((lane & 7) ^ ((lane >> 3) & 7)) * 8),
                     &Vlds[(w * 64 + i * 8) * 64]);
        }
        __syncthreads();  // B1: staging visible

        // adjacency (issued here so HBM latency overlaps S MFMAs)
        int av[4][4];
#pragma unroll
        for (int rgi = 0; rgi < 4; ++rgi)
#pragma unroll
            for (int jt = 0; jt < 4; ++jt)
                av[rgi][jt] = A[(size_t)(growb + rgi) * NN + j0 + jt * 16 + l15];

        // S = (Qh+Ql)·Kh^T : 16 rows x 64 cols per wave
        f32x4 accS[4];
#pragma unroll
        for (int jt = 0; jt < 4; ++jt) accS[jt] = fzero;
#pragma unroll
        for (int kc = 0; kc < 8; ++kc)
#pragma unroll
            for (int jt = 0; jt < 4; ++jt) {
                const int r = jt * 16 + l15;
                const f16x8 kf =
                    *(const f16x8*)&Klds[r * 256 + (((kc * 4 + quad) ^ (r & 7)) * 8)];
                accS[jt] = MFMA(qh[kc], kf, accS[jt]);
                accS[jt] = MFMA(ql[kc], kf, accS[jt]);
            }

        // wave-local online softmax (reduce over l15 lanes only)
        float alpha[4];
#pragma unroll
        for (int rgi = 0; rgi < 4; ++rgi) {
            const int gr = growb + rgi;
            float mx = -3.0e38f;
#pragma unroll
            for (int jt = 0; jt < 4; ++jt) {
                const int gc = j0 + jt * 16 + l15;
                float s = (av[rgi][jt] != 0 || gr == gc) ? accS[jt][rgi] : -3.0e38f;
                accS[jt][rgi] = s;
                mx = fmaxf(mx, s);
            }
#pragma unroll
            for (int off = 1; off < 16; off <<= 1) mx = fmaxf(mx, __shfl_xor(mx, off, 64));
            const float mnew = fmaxf(mrow[rgi], mx);
            alpha[rgi] = __expf(mrow[rgi] - mnew);
            mrow[rgi] = mnew;
            float rs = 0.f;
#pragma unroll
            for (int jt = 0; jt < 4; ++jt) {
                const float s = accS[jt][rgi];
                const float e = (s > -1.0e37f) ? __expf(s - mnew) : 0.f;
                rs += e;
                Pw[(quad * 4 + rgi) * 88 + jt * 16 + l15] = (f16)e;
            }
#pragma unroll
            for (int off = 1; off < 16; off <<= 1) rs += __shfl_xor(rs, off, 64);
            lrow[rgi] = lrow[rgi] * alpha[rgi] + rs;
        }
#pragma unroll
        for (int nt = 0; nt < 16; ++nt)
#pragma unroll
            for (int rgi = 0; rgi < 4; ++rgi) accO[nt][rgi] *= alpha[rgi];

        // P A-frags (per-wave LDS round trip; in-order LDS pipe, no barrier)
        f16x8 pf[2];
        pf[0] = *(const f16x8*)&Pw[l15 * 88 + quad * 8];
        pf[1] = *(const f16x8*)&Pw[l15 * 88 + 32 + quad * 8];

        // PV: 16 rows x 256 n per wave
#pragma unroll
        for (int nt = 0; nt < 16; ++nt)
#pragma unroll
            for (int kc2 = 0; kc2 < 2; ++kc2) {
                const int n = nt * 16 + l15;
                const f16x8 vf =
                    *(const f16x8*)&Vlds[n * 64 + (((kc2 * 4 + quad) ^ (n & 7)) * 8)];
                accO[nt] = MFMA(pf[kc2], vf, accO[nt]);
            }
        __syncthreads();  // B2: LDS free for next iter's staging
    }

    // write partials
#pragma unroll
    for (int nt = 0; nt < 16; ++nt)
#pragma unroll
        for (int rgi = 0; rgi < 4; ++rgi)
            pO[((size_t)cch * NN + growb + rgi) * DD + nt * 16 + l15] = accO[nt][rgi];
    if (l15 == 0) {
#pragma unroll
        for (int rgi = 0; rgi < 4; ++rgi) {
            pM[(size_t)cch * NN + growb + rgi] = mrow[rgi];
            pL[(size_t)cch * NN + growb + rgi] = lrow[rgi];
        }
    }
}

// ---------------- merge partials (8 rows/block) ----------------
__global__ __launch_bounds__(256) void merge_kernel(const float* __restrict__ pO,
                                                    const float* __restrict__ pM,
                                                    const float* __restrict__ pL,
                                                    float* __restrict__ out) {
    const int n = threadIdx.x;
#pragma unroll 1
    for (int rr = 0; rr < 8; ++rr) {
        const int row = blockIdx.x * 8 + rr;
        float mc[CCH], lc[CCH];
        float M = -3e38f;
#pragma unroll
        for (int c = 0; c < CCH; ++c) {
            mc[c] = pM[(size_t)c * NN + row];
            lc[c] = pL[(size_t)c * NN + row];
            M = fmaxf(M, mc[c]);
        }
        float L = 0.f, acc = 0.f;
#pragma unroll
        for (int c = 0; c < CCH; ++c) {
            const float wgt = __expf(mc[c] - M);
            L += wgt * lc[c];
            acc += wgt * pO[((size_t)c * NN + row) * DD + n];
        }
        out[(size_t)row * DD + n] = acc / L;
    }
}

extern "C" void kernel_launch(void* const* d_in, const int* in_sizes, int n_in,
                              void* d_out, int out_size, void* d_ws, size_t ws_size,
                              hipStream_t stream) {
    const float* X = (const float*)d_in[0];
    const int* A = (const int*)d_in[1];
    const float* Wq = (const float*)d_in[2];
    const float* Wk = (const float*)d_in[3];
    const float* Wv = (const float*)d_in[4];
    float* out = (float*)d_out;

    char* ws = (char*)d_ws;
    const size_t MB = 1ull << 20;
    f16* Xh = (f16*)(ws + 0 * MB);
    f16* Xl = (f16*)(ws + 4 * MB);
    f16* WtH = (f16*)(ws + 8 * MB);
    f16* WtL = (f16*)(ws + 8 * MB + 512 * 1024);
    f16* Qh = (f16*)(ws + 9 * MB);
    f16* Ql = (f16*)(ws + 13 * MB);
    f16* Kh = (f16*)(ws + 17 * MB);
    f16* Vt = (f16*)(ws + 21 * MB);
    float* pO = (float*)(ws + 25 * MB);
    float* pM = (float*)(ws + 57 * MB);
    float* pL = (float*)(ws + 57 * MB + 256 * 1024);
    (void)ws_size; (void)in_sizes; (void)n_in; (void)out_size;

    splitX_kernel<<<2048, 256, 0, stream>>>((const float4*)X, (f16x4*)Xh, (f16x4*)Xl);
    splitW_kernel<<<768, 256, 0, stream>>>(Wq, Wk, Wv, WtH, WtL);
    qkv_kernel<<<dim3(NN / 64, 3), 256, 0, stream>>>(Xh, Xl, WtH, WtL, Qh, Ql, Kh, Vt);
    flash_kernel<<<(NN / BR) * CCH, 256, 0, stream>>>(Qh, Ql, Kh, Vt, A, pO, pM, pL);
    merge_kernel<<<NN / 8, 256, 0, stream>>>(pO, pM, pL, out);
}